// Round 10
// baseline (356.210 us; speedup 1.0000x reference)
//
#include <hip/hip_runtime.h>
#include <math.h>

// ---- problem constants (fixed shapes from reference setup_inputs) ----
#define BATCH      4
#define N_RPN      36864
#define NMS_TOPN   300
#define IOU_THR    0.5f
#define TOTAL_LABELS 21
#define TOTAL_POS  64
#define TOTAL_BOX  128          // TOTAL_POS + TOTAL_NEG
#define GT_M       16
#define FM_H       64
#define FM_W       64
#define FM_C       512
#define POOL_H     7
#define POOL_W     7
#define MCAP       4096         // top-K candidates kept for greedy NMS
#define MWORDS     (MCAP / 64)  // 64 suppression words per row
#define NBUCK      1024
#define JCHUNKS    16           // rank partial decomposition (MCAP/256)
#define PICKS      32           // NMS scan: candidates per memory round

typedef unsigned long long u64;

// out sizes (elements)
#define OUT_POOL_ELEMS   ((size_t)BATCH * TOTAL_BOX * POOL_H * POOL_W * FM_C)   // 12,845,056
#define OUT_DELTA_ELEMS  ((size_t)BATCH * TOTAL_BOX * TOTAL_LABELS * 4)         // 43,008

// ------------------------------------------------------------------
// Kernel 1a: histogram -> threshold -> compact keys to global.
// One 1024-thread block per batch. (unchanged from passing R9)
// ------------------------------------------------------------------
__global__ __launch_bounds__(1024) void compact_kernel(
    const float* __restrict__ scores, u64* __restrict__ keysG,
    int* __restrict__ mCounts)
{
    const int b = blockIdx.x;
    const int t = threadIdx.x;
    const int lane = t & 63;
    const int wave = t >> 6;
    __shared__ unsigned hist[NBUCK];
    __shared__ unsigned s_suf[NBUCK];
    __shared__ unsigned s_wincl[16];
    __shared__ int s_cnt, s_thresh;

    hist[t] = 0u;
    if (t == 0) { s_cnt = 0; s_thresh = NBUCK - 1; }
    __syncthreads();

    const float* sc = scores + (size_t)b * N_RPN;
    for (int i = t; i < N_RPN; i += 1024) {
        int bk = (int)(sc[i] * 1024.0f);
        bk = min(max(bk, 0), NBUCK - 1);
        atomicAdd(&hist[bk], 1u);
    }
    __syncthreads();

    // suffix-inclusive scan: wave-internal via shfl_down, then wave sums
    unsigned v = hist[t];
    #pragma unroll
    for (int off = 1; off < 64; off <<= 1) {
        unsigned o = __shfl_down(v, off, 64);
        if (lane + off < 64) v += o;
    }
    if (lane == 0) s_wincl[wave] = v;     // wave total
    __syncthreads();
    if (wave == 0 && lane < 16) {
        unsigned wv = s_wincl[lane];
        #pragma unroll
        for (int off = 1; off < 16; off <<= 1) {
            unsigned o = __shfl_down(wv, off, 64);
            if (lane + off < 16) wv += o;
        }
        s_wincl[lane] = wv;               // inclusive suffix over waves
    }
    __syncthreads();
    unsigned suf = v + ((wave < 15) ? s_wincl[wave + 1] : 0u);
    s_suf[t] = suf;
    __syncthreads();
    if (suf <= MCAP && (t == 0 || s_suf[t - 1] > MCAP)) s_thresh = t;
    __syncthreads();
    const int thresh = s_thresh;

    u64* kg = keysG + (size_t)b * MCAP;
    for (int i = t; i < N_RPN; i += 1024) {
        float s = sc[i];
        int bk = min(max((int)(s * 1024.0f), 0), NBUCK - 1);
        if (bk >= thresh) {
            int p = atomicAdd(&s_cnt, 1);
            // descending score, ascending index => key desc; keys unique, >0
            kg[p] = ((u64)__float_as_uint(s) << 32) | (unsigned)(~(unsigned)i);
        }
    }
    __syncthreads();
    const int M = s_cnt;
    for (int p = M + t; p < MCAP; p += 1024) kg[p] = 0ULL;
    if (t == 0) mCounts[b] = M;
}

// ------------------------------------------------------------------
// Kernel 1b: partial rank counts, 2-D decomposition for TLP.
// (unchanged from passing R9)
// ------------------------------------------------------------------
__global__ __launch_bounds__(256) void rank_partial_kernel(
    const u64* __restrict__ keysG, int* __restrict__ partial)
{
    const int b  = blockIdx.z;
    const int jc = blockIdx.y;
    const int ic = blockIdx.x;
    const int t  = threadIdx.x;
    __shared__ u64 s_j[256];
    const u64* kg = keysG + (size_t)b * MCAP;
    s_j[t] = kg[jc * 256 + t];
    __syncthreads();

    const int i = ic * 256 + t;
    const u64 ki = kg[i];
    const int jbase = jc * 256;
    int cnt = 0;
    const ulonglong2* k2 = (const ulonglong2*)s_j;
    #pragma unroll 8
    for (int j2 = 0; j2 < 128; ++j2) {
        ulonglong2 kk = k2[j2];           // wave-uniform -> LDS broadcast
        int j = jbase + j2 * 2;
        cnt += (kk.x > ki) || (kk.x == ki && j < i);
        cnt += (kk.y > ki) || (kk.y == ki && (j + 1) < i);
    }
    partial[((size_t)b * JCHUNKS + jc) * MCAP + i] = cnt;
}

// ------------------------------------------------------------------
// Kernel 1c: rank = sum of partials -> decode box into
// sortedBoxes[rank]. (unchanged from passing R9)
// ------------------------------------------------------------------
__global__ __launch_bounds__(256) void rank_finalize_kernel(
    const u64* __restrict__ keysG, const float* __restrict__ anchors,
    const float* __restrict__ deltas, const int* __restrict__ mCounts,
    const int* __restrict__ partial, float4* __restrict__ sortedBoxes)
{
    const int b = blockIdx.y;
    const int t = threadIdx.x;
    const int i = blockIdx.x * 256 + t;

    int rank = 0;
    #pragma unroll
    for (int jc = 0; jc < JCHUNKS; ++jc)
        rank += partial[((size_t)b * JCHUNKS + jc) * MCAP + i];

    const u64 ki = keysG[(size_t)b * MCAP + i];
    const int M = mCounts[b];
    float4 o = make_float4(0.f, 0.f, 0.f, 0.f);
    if (i < M) {
        unsigned idx = ~(unsigned)(ki & 0xFFFFFFFFULL);
        const float* a = anchors + ((size_t)b * N_RPN + idx) * 4;
        const float* d = deltas  + ((size_t)b * N_RPN + idx) * 4;
        float aw  = a[3] - a[1];
        float ah  = a[2] - a[0];
        float acx = a[1] + 0.5f * aw;
        float acy = a[0] + 0.5f * ah;
        float ww  = expf(d[3]) * aw;
        float hh  = expf(d[2]) * ah;
        float cx  = d[1] * aw + acx;
        float cy  = d[0] * ah + acy;
        float y1  = cy - 0.5f * hh;
        float x1  = cx - 0.5f * ww;
        o = make_float4(y1, x1, y1 + hh, x1 + ww);
    }
    sortedBoxes[(size_t)b * MCAP + rank] = o;
}

// ------------------------------------------------------------------
// Kernel 2: suppression bitmask over top-4096, layout mk[word][row].
// (unchanged from passing R9)
// ------------------------------------------------------------------
__global__ __launch_bounds__(256) void nms_mask_kernel(
    const float4* __restrict__ sortedBoxes, u64* __restrict__ mask)
{
    const int b  = blockIdx.z;
    const int r0 = blockIdx.x * 64;
    const int c0 = blockIdx.y * 256;
    u64* mk = mask + (size_t)b * (MWORDS * MCAP);
    const int t  = threadIdx.x;
    const int lr = t & 63;
    const int wq = t >> 6;
    const int r  = r0 + lr;
    const int w  = (c0 >> 6) + wq;

    if (c0 + 255 <= r0) {
        mk[(size_t)w * MCAP + r] = 0ULL;
        return;
    }
    __shared__ float4 s_c[256];
    const float4* sb = sortedBoxes + (size_t)b * MCAP;
    s_c[t] = sb[c0 + t];
    float4 bi = sb[r];
    __syncthreads();

    float ai = (bi.z - bi.x) * (bi.w - bi.y);
    u64 bits = 0ULL;
    const int jb = w * 64;
    if (jb + 63 > r) {
        for (int k = 0; k < 64; ++k) {
            float4 bj = s_c[wq * 64 + k];
            float yt = fmaxf(bi.x, bj.x);
            float xt = fmaxf(bi.y, bj.y);
            float yb = fminf(bi.z, bj.z);
            float xb = fminf(bi.w, bj.w);
            float inter = fmaxf(yb - yt, 0.f) * fmaxf(xb - xt, 0.f);
            float aj = (bj.z - bj.x) * (bj.w - bj.y);
            float un = ai + aj - inter;
            bool sup = (jb + k > r) && (un > 0.f) && ((inter / un) > IOU_THR);
            bits |= ((u64)sup) << k;
        }
    }
    mk[(size_t)w * MCAP + r] = bits;
}

// ------------------------------------------------------------------
// Kernel 3: greedy scan, one wave per batch. NEW extraction: per
// ROUND prefix-popcount (7 shfls total) instead of per PICK 2 shfls
// (R9: 16 picks x 2 ds_bpermute @~120cyc dependent = the 82us chain).
// 32 picks/round; commits validated vs intra-round committed-OR via
// cheap __ballot (VALU compare, not shfl) -> exact greedy.
// ------------------------------------------------------------------
__global__ __launch_bounds__(64) void nms_scan_kernel(
    const float4* __restrict__ sortedBoxes, const int* __restrict__ mCounts,
    const u64* __restrict__ mask, float4* __restrict__ selBoxes)
{
    const int b = blockIdx.x;
    const int l = threadIdx.x;
    const u64* mkl = mask + (size_t)b * (MWORDS * MCAP) + (size_t)l * MCAP;
    __shared__ int s_sel[NMS_TOPN];
    __shared__ int s_idx[PICKS];
    const int M = mCounts[b];
    const int lo = l * 64;
    u64 bound = (lo + 64 <= M) ? ~0ULL
              : ((lo >= M) ? 0ULL : ((1ULL << (M - lo)) - 1ULL));
    u64 sup = 0ULL;
    int cnt = 0;

    while (cnt < NMS_TOPN) {
        const u64 avw = ~sup & bound;
        // ---- extraction: first PICKS alive indices, ascending ----
        int cl = __popcll(avw);
        int pfx = cl;                      // inclusive prefix over lanes
        #pragma unroll
        for (int off = 1; off < 64; off <<= 1) {
            int o = __shfl_up(pfx, off, 64);
            if (l >= off) pfx += o;
        }
        const int total = __shfl(pfx, 63, 64);
        if (total == 0) break;
        const int navail = min(total, PICKS);
        int r = pfx - cl;                  // exclusive prefix (my first rank)
        if (r < PICKS && cl > 0) {
            u64 w = avw;
            while (w && r < PICKS) {
                int bit = __ffsll((long long)w) - 1;
                s_idx[r] = lo + bit;
                w &= w - 1;
                ++r;
            }
        }
        __syncthreads();

        int idx_r[PICKS];
        #pragma unroll
        for (int m = 0; m < PICKS; ++m)
            idx_r[m] = (m < navail) ? s_idx[m] : -1;   // uniform LDS broadcast
        __syncthreads();

        // ---- parallel row loads (one memory latency) ----
        u64 rows[PICKS];
        #pragma unroll
        for (int m = 0; m < PICKS; ++m)
            rows[m] = (idx_r[m] >= 0) ? mkl[idx_r[m]] : 0ULL;

        // ---- sequential commit vs this-round committed rows ----
        u64 acc = 0ULL;
        #pragma unroll
        for (int m = 0; m < PICKS; ++m) {
            int im = idx_r[m];
            if (im < 0 || cnt >= NMS_TOPN) break;
            int Lm = im >> 6, bm = im & 63;
            u64 kb = __ballot((l == Lm) && ((acc >> bm) & 1ULL));
            if (kb == 0ULL) {              // survives committed rows -> pick
                if (l == 0) s_sel[cnt] = im;
                cnt++;
                acc |= rows[m];
                if (l == Lm) acc |= (1ULL << bm);   // mark picked
            }
        }
        sup |= acc;
    }
    __syncthreads();

    for (int r = l; r < NMS_TOPN; r += 64) {
        float4 o = make_float4(0.f, 0.f, 0.f, 0.f);
        if (r < cnt) {
            float4 bx = sortedBoxes[(size_t)b * MCAP + s_sel[r]];
            o.x = fminf(fmaxf(bx.x, 0.f), 1.f);
            o.y = fminf(fmaxf(bx.y, 0.f), 1.f);
            o.z = fminf(fmaxf(bx.z, 0.f), 1.f);
            o.w = fminf(fmaxf(bx.w, 0.f), 1.f);
        }
        selBoxes[(size_t)b * NMS_TOPN + r] = o;
    }
}

// ------------------------------------------------------------------
// Kernel 4: per-batch RoI selection (unchanged).
// ------------------------------------------------------------------
__global__ __launch_bounds__(512) void select_kernel(
    const float4* __restrict__ selBoxes, const float* __restrict__ gt_boxes,
    const int* __restrict__ gt_labels, float4* __restrict__ roiBoxes,
    float4* __restrict__ gtMap, int* __restrict__ labMap)
{
    const int b = blockIdx.x;
    const int t = threadIdx.x;
    __shared__ float4 sb[NMS_TOPN];
    __shared__ float4 gt[GT_M];
    __shared__ float  merged[NMS_TOPN];
    __shared__ int    mgt[NMS_TOPN];
    __shared__ short  order[TOTAL_BOX];

    if (t < NMS_TOPN) sb[t] = selBoxes[(size_t)b * NMS_TOPN + t];
    if (t < GT_M) gt[t] = ((const float4*)gt_boxes)[b * GT_M + t];
    __syncthreads();

    if (t < NMS_TOPN) {
        float4 bx = sb[t];
        float a1 = (bx.z - bx.x) * (bx.w - bx.y);
        float best = -1.f; int arg = 0;
        for (int j = 0; j < GT_M; ++j) {
            float4 g = gt[j];
            float yt = fmaxf(bx.x, g.x), xt = fmaxf(bx.y, g.y);
            float yb = fminf(bx.z, g.z), xb = fminf(bx.w, g.w);
            float inter = fmaxf(yb - yt, 0.f) * fmaxf(xb - xt, 0.f);
            float a2 = (g.z - g.x) * (g.w - g.y);
            float un = a1 + a2 - inter;
            float iou = (un > 0.f) ? (inter / un) : 0.f;
            if (iou > best) { best = iou; arg = j; }
        }
        merged[t] = best; mgt[t] = arg;
    }
    __syncthreads();

    if (t < NMS_TOPN) {
        float mi = merged[t];
        int rank = 0;
        for (int j = 0; j < NMS_TOPN; ++j) {
            float mj = merged[j];
            rank += (mj > mi) || (mj == mi && j < t);
        }
        if (rank < TOTAL_BOX) order[rank] = (short)t;
    }
    __syncthreads();

    if (t < TOTAL_BOX) {
        int i = order[t];
        roiBoxes[(size_t)b * TOTAL_BOX + t] = sb[i];
        float4 g = make_float4(0.f, 0.f, 0.f, 0.f);
        int lab = TOTAL_LABELS - 1;
        if (t < TOTAL_POS) {
            int gi = mgt[i];
            g = gt[gi];
            lab = gt_labels[b * GT_M + gi];
        }
        gtMap[(size_t)b * TOTAL_BOX + t] = g;
        labMap[b * TOTAL_BOX + t] = lab;
    }
}

// ------------------------------------------------------------------
// Kernel 5: crop_and_resize bilinear 7x7 pooling (unchanged).
// ------------------------------------------------------------------
__global__ __launch_bounds__(256) void pool_kernel(
    const float* __restrict__ fm, const float4* __restrict__ roiBoxes,
    float* __restrict__ out)
{
    const int b  = blockIdx.y;
    const int r  = blockIdx.x / POOL_H;
    const int py = blockIdx.x % POOL_H;
    const int t  = threadIdx.x;

    float4 bx = roiBoxes[(size_t)b * TOTAL_BOX + r];
    float y1 = bx.x, x1 = bx.y, y2 = bx.z, x2 = bx.w;

    float iy = (float)py / 6.0f;
    float cy = (y2 - y1) * 63.0f;
    float ys = y1 * 63.0f + iy * cy;
    float fy0 = floorf(ys);
    float wy = ys - fy0;
    int y0i = min(max((int)fy0, 0), FM_H - 1);
    int y1i = min(y0i + 1, FM_H - 1);
    bool vy = (ys >= 0.f) && (ys <= 63.f);

    float cx = (x2 - x1) * 63.0f;
    const float2* f2 = (const float2*)fm;
    float2* o2 = (float2*)out;
    size_t obase = ((((size_t)b * TOTAL_BOX + r) * POOL_H + py) * POOL_W) * 256 + t;
    size_t brow = (size_t)b * FM_H;

    for (int px = 0; px < POOL_W; ++px) {
        float ix = (float)px / 6.0f;
        float xs = x1 * 63.0f + ix * cx;
        float fx0 = floorf(xs);
        float wx = xs - fx0;
        int x0i = min(max((int)fx0, 0), FM_W - 1);
        int x1i = min(x0i + 1, FM_W - 1);
        bool vx = (xs >= 0.f) && (xs <= 63.f);

        float2 g00 = f2[((brow + y0i) * FM_W + x0i) * 256 + t];
        float2 g01 = f2[((brow + y0i) * FM_W + x1i) * 256 + t];
        float2 g10 = f2[((brow + y1i) * FM_W + x0i) * 256 + t];
        float2 g11 = f2[((brow + y1i) * FM_W + x1i) * 256 + t];

        float tx = 1.f - wx, ty = 1.f - wy;
        float top0 = g00.x * tx + g01.x * wx;
        float top1 = g00.y * tx + g01.y * wx;
        float bot0 = g10.x * tx + g11.x * wx;
        float bot1 = g10.y * tx + g11.y * wx;
        float o0 = top0 * ty + bot0 * wy;
        float o1 = top1 * ty + bot1 * wy;
        if (!(vy && vx)) { o0 = 0.f; o1 = 0.f; }
        o2[obase + (size_t)px * 256] = make_float2(o0, o1);
    }
}

// ------------------------------------------------------------------
// Kernel 6: deltas + one-hot scatter (unchanged).
// ------------------------------------------------------------------
__global__ __launch_bounds__(256) void finalize_kernel(
    const float4* __restrict__ roiBoxes, const float4* __restrict__ gtMap,
    const int* __restrict__ labMap, float* __restrict__ out_deltas,
    float* __restrict__ out_labels)
{
    int tid = blockIdx.x * blockDim.x + threadIdx.x;
    if (tid >= BATCH * TOTAL_BOX) return;
    float4 bb = roiBoxes[tid];
    float4 g  = gtMap[tid];
    int lab   = labMap[tid];

    float bw = bb.w - bb.y, bh = bb.z - bb.x;
    float bcx = bb.y + 0.5f * bw, bcy = bb.x + 0.5f * bh;
    float gw = g.w - g.y, gh = g.z - g.x;
    float gcx = g.y + 0.5f * gw, gcy = g.x + 0.5f * gh;
    float bw2 = (bw == 0.f) ? 0.001f : bw;
    float bh2 = (bh == 0.f) ? 0.001f : bh;
    float dx = (gw == 0.f) ? 0.f : (gcx - bcx) / bw2;
    float dy = (gh == 0.f) ? 0.f : (gcy - bcy) / bh2;
    float dw = (gw == 0.f) ? 0.f : logf(fmaxf(gw, 1e-12f) / bw2);
    float dh = (gh == 0.f) ? 0.f : logf(fmaxf(gh, 1e-12f) / bh2);
    float dlt[4] = {dy, dx, dh, dw};

    float* od = out_deltas + (size_t)tid * (TOTAL_LABELS * 4);
    for (int k = 0; k < TOTAL_LABELS * 4; ++k)
        od[k] = ((k >> 2) == lab) ? dlt[k & 3] : 0.f;
    float* ol = out_labels + (size_t)tid * TOTAL_LABELS;
    for (int c = 0; c < TOTAL_LABELS; ++c)
        ol[c] = (c == lab) ? 1.0f : 0.0f;
}

// ------------------------------------------------------------------
extern "C" void kernel_launch(void* const* d_in, const int* in_sizes, int n_in,
                              void* d_out, int out_size, void* d_ws, size_t ws_size,
                              hipStream_t stream) {
    (void)in_sizes; (void)n_in; (void)out_size; (void)ws_size;
    const float* fm         = (const float*)d_in[0];
    const float* rpn_deltas = (const float*)d_in[1];
    const float* rpn_scores = (const float*)d_in[2];
    const float* anchors    = (const float*)d_in[3];
    const float* gt_boxes   = (const float*)d_in[4];
    const int*   gt_labels  = (const int*)d_in[5];
    float* out = (float*)d_out;

    char* w = (char*)d_ws;
    size_t off = 0;
    auto take = [&](size_t bytes) -> char* {
        char* p = w + off;
        off = (off + bytes + 255) & ~(size_t)255;
        return p;
    };
    float4* sortedBoxes = (float4*)take((size_t)BATCH * MCAP * 16);
    u64*    keysG       = (u64*)take((size_t)BATCH * MCAP * 8);
    int*    mCounts     = (int*)take(BATCH * sizeof(int));
    int*    partial     = (int*)take((size_t)BATCH * JCHUNKS * MCAP * 4);  // 1 MB
    float4* selBoxes    = (float4*)take((size_t)BATCH * NMS_TOPN * 16);
    float4* roiBoxes    = (float4*)take((size_t)BATCH * TOTAL_BOX * 16);
    float4* gtMap       = (float4*)take((size_t)BATCH * TOTAL_BOX * 16);
    int*    labMap      = (int*)take((size_t)BATCH * TOTAL_BOX * 4);
    u64*    mask        = (u64*)take((size_t)BATCH * MWORDS * MCAP * 8);   // 8 MB

    compact_kernel<<<BATCH, 1024, 0, stream>>>(rpn_scores, keysG, mCounts);
    rank_partial_kernel<<<dim3(MCAP / 256, JCHUNKS, BATCH), 256, 0, stream>>>(
        keysG, partial);
    rank_finalize_kernel<<<dim3(MCAP / 256, BATCH), 256, 0, stream>>>(
        keysG, anchors, rpn_deltas, mCounts, partial, sortedBoxes);
    nms_mask_kernel<<<dim3(MCAP / 64, MCAP / 256, BATCH), 256, 0, stream>>>(
        sortedBoxes, mask);
    nms_scan_kernel<<<BATCH, 64, 0, stream>>>(sortedBoxes, mCounts, mask, selBoxes);
    select_kernel<<<BATCH, 512, 0, stream>>>(selBoxes, gt_boxes, gt_labels,
                                             roiBoxes, gtMap, labMap);
    pool_kernel<<<dim3(TOTAL_BOX * POOL_H, BATCH), 256, 0, stream>>>(fm, roiBoxes, out);
    finalize_kernel<<<2, 256, 0, stream>>>(roiBoxes, gtMap, labMap,
                                           out + OUT_POOL_ELEMS,
                                           out + OUT_POOL_ELEMS + OUT_DELTA_ELEMS);
}

// Round 11
// 278.709 us; speedup vs baseline: 1.2781x; 1.2781x over previous
//
#include <hip/hip_runtime.h>
#include <math.h>

// ---- problem constants (fixed shapes from reference setup_inputs) ----
#define BATCH      4
#define N_RPN      36864
#define NMS_TOPN   300
#define IOU_THR    0.5f
#define TOTAL_LABELS 21
#define TOTAL_POS  64
#define TOTAL_BOX  128          // TOTAL_POS + TOTAL_NEG
#define GT_M       16
#define FM_H       64
#define FM_W       64
#define FM_C       512
#define POOL_H     7
#define POOL_W     7
#define MCAP       4096         // top-K candidates kept for greedy NMS
#define MWORDS     (MCAP / 64)  // 64 suppression words per row
#define NBUCK      1024
#define JCHUNKS    16           // rank partial decomposition (MCAP/256)
#define PICKS      16           // NMS scan: candidates per memory round

typedef unsigned long long u64;

// out sizes (elements)
#define OUT_POOL_ELEMS   ((size_t)BATCH * TOTAL_BOX * POOL_H * POOL_W * FM_C)   // 12,845,056
#define OUT_DELTA_ELEMS  ((size_t)BATCH * TOTAL_BOX * TOTAL_LABELS * 4)         // 43,008

// ------------------------------------------------------------------
// Kernel 1a: histogram -> threshold -> compact keys to global.
// (unchanged from passing R9/R10)
// ------------------------------------------------------------------
__global__ __launch_bounds__(1024) void compact_kernel(
    const float* __restrict__ scores, u64* __restrict__ keysG,
    int* __restrict__ mCounts)
{
    const int b = blockIdx.x;
    const int t = threadIdx.x;
    const int lane = t & 63;
    const int wave = t >> 6;
    __shared__ unsigned hist[NBUCK];
    __shared__ unsigned s_suf[NBUCK];
    __shared__ unsigned s_wincl[16];
    __shared__ int s_cnt, s_thresh;

    hist[t] = 0u;
    if (t == 0) { s_cnt = 0; s_thresh = NBUCK - 1; }
    __syncthreads();

    const float* sc = scores + (size_t)b * N_RPN;
    for (int i = t; i < N_RPN; i += 1024) {
        int bk = (int)(sc[i] * 1024.0f);
        bk = min(max(bk, 0), NBUCK - 1);
        atomicAdd(&hist[bk], 1u);
    }
    __syncthreads();

    // suffix-inclusive scan: wave-internal via shfl_down, then wave sums
    unsigned v = hist[t];
    #pragma unroll
    for (int off = 1; off < 64; off <<= 1) {
        unsigned o = __shfl_down(v, off, 64);
        if (lane + off < 64) v += o;
    }
    if (lane == 0) s_wincl[wave] = v;     // wave total
    __syncthreads();
    if (wave == 0 && lane < 16) {
        unsigned wv = s_wincl[lane];
        #pragma unroll
        for (int off = 1; off < 16; off <<= 1) {
            unsigned o = __shfl_down(wv, off, 64);
            if (lane + off < 16) wv += o;
        }
        s_wincl[lane] = wv;               // inclusive suffix over waves
    }
    __syncthreads();
    unsigned suf = v + ((wave < 15) ? s_wincl[wave + 1] : 0u);
    s_suf[t] = suf;
    __syncthreads();
    if (suf <= MCAP && (t == 0 || s_suf[t - 1] > MCAP)) s_thresh = t;
    __syncthreads();
    const int thresh = s_thresh;

    u64* kg = keysG + (size_t)b * MCAP;
    for (int i = t; i < N_RPN; i += 1024) {
        float s = sc[i];
        int bk = min(max((int)(s * 1024.0f), 0), NBUCK - 1);
        if (bk >= thresh) {
            int p = atomicAdd(&s_cnt, 1);
            // descending score, ascending index => key desc; keys unique, >0
            kg[p] = ((u64)__float_as_uint(s) << 32) | (unsigned)(~(unsigned)i);
        }
    }
    __syncthreads();
    const int M = s_cnt;
    for (int p = M + t; p < MCAP; p += 1024) kg[p] = 0ULL;
    if (t == 0) mCounts[b] = M;
}

// ------------------------------------------------------------------
// Kernel 1b: partial rank counts, 2-D decomposition for TLP.
// (unchanged from passing R9/R10)
// ------------------------------------------------------------------
__global__ __launch_bounds__(256) void rank_partial_kernel(
    const u64* __restrict__ keysG, int* __restrict__ partial)
{
    const int b  = blockIdx.z;
    const int jc = blockIdx.y;
    const int ic = blockIdx.x;
    const int t  = threadIdx.x;
    __shared__ u64 s_j[256];
    const u64* kg = keysG + (size_t)b * MCAP;
    s_j[t] = kg[jc * 256 + t];
    __syncthreads();

    const int i = ic * 256 + t;
    const u64 ki = kg[i];
    const int jbase = jc * 256;
    int cnt = 0;
    const ulonglong2* k2 = (const ulonglong2*)s_j;
    #pragma unroll 8
    for (int j2 = 0; j2 < 128; ++j2) {
        ulonglong2 kk = k2[j2];           // wave-uniform -> LDS broadcast
        int j = jbase + j2 * 2;
        cnt += (kk.x > ki) || (kk.x == ki && j < i);
        cnt += (kk.y > ki) || (kk.y == ki && (j + 1) < i);
    }
    partial[((size_t)b * JCHUNKS + jc) * MCAP + i] = cnt;
}

// ------------------------------------------------------------------
// Kernel 1c: rank = sum of partials -> decode box into
// sortedBoxes[rank]. (unchanged from passing R9/R10)
// ------------------------------------------------------------------
__global__ __launch_bounds__(256) void rank_finalize_kernel(
    const u64* __restrict__ keysG, const float* __restrict__ anchors,
    const float* __restrict__ deltas, const int* __restrict__ mCounts,
    const int* __restrict__ partial, float4* __restrict__ sortedBoxes)
{
    const int b = blockIdx.y;
    const int t = threadIdx.x;
    const int i = blockIdx.x * 256 + t;

    int rank = 0;
    #pragma unroll
    for (int jc = 0; jc < JCHUNKS; ++jc)
        rank += partial[((size_t)b * JCHUNKS + jc) * MCAP + i];

    const u64 ki = keysG[(size_t)b * MCAP + i];
    const int M = mCounts[b];
    float4 o = make_float4(0.f, 0.f, 0.f, 0.f);
    if (i < M) {
        unsigned idx = ~(unsigned)(ki & 0xFFFFFFFFULL);
        const float* a = anchors + ((size_t)b * N_RPN + idx) * 4;
        const float* d = deltas  + ((size_t)b * N_RPN + idx) * 4;
        float aw  = a[3] - a[1];
        float ah  = a[2] - a[0];
        float acx = a[1] + 0.5f * aw;
        float acy = a[0] + 0.5f * ah;
        float ww  = expf(d[3]) * aw;
        float hh  = expf(d[2]) * ah;
        float cx  = d[1] * aw + acx;
        float cy  = d[0] * ah + acy;
        float y1  = cy - 0.5f * hh;
        float x1  = cx - 0.5f * ww;
        o = make_float4(y1, x1, y1 + hh, x1 + ww);
    }
    sortedBoxes[(size_t)b * MCAP + rank] = o;
}

// ------------------------------------------------------------------
// Kernel 2: suppression bitmask over top-4096, layout mk[word][row].
// (unchanged from passing R9/R10)
// ------------------------------------------------------------------
__global__ __launch_bounds__(256) void nms_mask_kernel(
    const float4* __restrict__ sortedBoxes, u64* __restrict__ mask)
{
    const int b  = blockIdx.z;
    const int r0 = blockIdx.x * 64;
    const int c0 = blockIdx.y * 256;
    u64* mk = mask + (size_t)b * (MWORDS * MCAP);
    const int t  = threadIdx.x;
    const int lr = t & 63;
    const int wq = t >> 6;
    const int r  = r0 + lr;
    const int w  = (c0 >> 6) + wq;

    if (c0 + 255 <= r0) {
        mk[(size_t)w * MCAP + r] = 0ULL;
        return;
    }
    __shared__ float4 s_c[256];
    const float4* sb = sortedBoxes + (size_t)b * MCAP;
    s_c[t] = sb[c0 + t];
    float4 bi = sb[r];
    __syncthreads();

    float ai = (bi.z - bi.x) * (bi.w - bi.y);
    u64 bits = 0ULL;
    const int jb = w * 64;
    if (jb + 63 > r) {
        for (int k = 0; k < 64; ++k) {
            float4 bj = s_c[wq * 64 + k];
            float yt = fmaxf(bi.x, bj.x);
            float xt = fmaxf(bi.y, bj.y);
            float yb = fminf(bi.z, bj.z);
            float xb = fminf(bi.w, bj.w);
            float inter = fmaxf(yb - yt, 0.f) * fmaxf(xb - xt, 0.f);
            float aj = (bj.z - bj.x) * (bj.w - bj.y);
            float un = ai + aj - inter;
            bool sup = (jb + k > r) && (un > 0.f) && ((inter / un) > IOU_THR);
            bits |= ((u64)sup) << k;
        }
    }
    mk[(size_t)w * MCAP + r] = bits;
}

// ------------------------------------------------------------------
// Kernel 3: greedy scan, one wave per batch. Prefix-popcount
// extraction (7 shfls/round), then PICKS=16 rows in NAMED registers
// (macro-unrolled, zero break statements, no arrays) so the compiler
// cannot spill to scratch (R10: rows[32] -> 64KB scratch writes,
// WRITE_SIZE 18.75->82.75KB, 150us). Commit validated vs intra-round
// committed-OR via __ballot -> exact greedy.
// ------------------------------------------------------------------
__global__ __launch_bounds__(64) void nms_scan_kernel(
    const float4* __restrict__ sortedBoxes, const int* __restrict__ mCounts,
    const u64* __restrict__ mask, float4* __restrict__ selBoxes)
{
    const int b = blockIdx.x;
    const int l = threadIdx.x;
    const u64* mkl = mask + (size_t)b * (MWORDS * MCAP) + (size_t)l * MCAP;
    __shared__ int s_sel[NMS_TOPN];
    __shared__ int s_idx[PICKS];
    const int M = mCounts[b];
    const int lo = l * 64;
    u64 bound = (lo + 64 <= M) ? ~0ULL
              : ((lo >= M) ? 0ULL : ((1ULL << (M - lo)) - 1ULL));
    u64 sup = 0ULL;
    int cnt = 0;

    while (cnt < NMS_TOPN) {
        const u64 avw = ~sup & bound;
        // ---- extraction: first PICKS alive indices, ascending ----
        const int cl = __popcll(avw);
        int pfx = cl;                      // inclusive prefix over lanes
        #pragma unroll
        for (int off = 1; off < 64; off <<= 1) {
            int o = __shfl_up(pfx, off, 64);
            if (l >= off) pfx += o;
        }
        const int total = __shfl(pfx, 63, 64);
        if (total == 0) break;
        const int navail = min(total, PICKS);
        int r = pfx - cl;                  // exclusive prefix (my first rank)
        if (r < PICKS && cl > 0) {
            u64 w = avw;
            while (w && r < PICKS) {
                int bit = __ffsll((long long)w) - 1;
                s_idx[r] = lo + bit;
                w &= w - 1;
                ++r;
            }
        }
        if (l < PICKS && l >= navail) s_idx[l] = -1;   // pad unused slots
        __syncthreads();

        // ---- indices into named registers (LDS broadcast reads) ----
        #define RD_IDX(m) const int i##m = s_idx[m];
        RD_IDX(0)  RD_IDX(1)  RD_IDX(2)  RD_IDX(3)
        RD_IDX(4)  RD_IDX(5)  RD_IDX(6)  RD_IDX(7)
        RD_IDX(8)  RD_IDX(9)  RD_IDX(10) RD_IDX(11)
        RD_IDX(12) RD_IDX(13) RD_IDX(14) RD_IDX(15)
        #undef RD_IDX
        __syncthreads();

        // ---- 16 independent row loads (single memory latency) ----
        #define RD_ROW(m) const u64 row##m = (i##m >= 0) ? mkl[i##m] : 0ULL;
        RD_ROW(0)  RD_ROW(1)  RD_ROW(2)  RD_ROW(3)
        RD_ROW(4)  RD_ROW(5)  RD_ROW(6)  RD_ROW(7)
        RD_ROW(8)  RD_ROW(9)  RD_ROW(10) RD_ROW(11)
        RD_ROW(12) RD_ROW(13) RD_ROW(14) RD_ROW(15)
        #undef RD_ROW

        // ---- sequential commit vs this-round committed rows ----
        u64 acc = 0ULL;
        #define COMMIT(m)                                                    \
        {                                                                    \
            const int im = i##m;                                             \
            const bool can = (im >= 0) && (cnt < NMS_TOPN);                  \
            const int Lm = im >> 6, bm = im & 63;                            \
            u64 kb = __ballot(can && (l == Lm) && ((acc >> bm) & 1ULL));     \
            if (can && kb == 0ULL) {                                         \
                if (l == 0) s_sel[cnt] = im;                                 \
                cnt++;                                                       \
                acc |= row##m;                                               \
                if (l == Lm) acc |= (1ULL << bm);                            \
            }                                                                \
        }
        COMMIT(0)  COMMIT(1)  COMMIT(2)  COMMIT(3)
        COMMIT(4)  COMMIT(5)  COMMIT(6)  COMMIT(7)
        COMMIT(8)  COMMIT(9)  COMMIT(10) COMMIT(11)
        COMMIT(12) COMMIT(13) COMMIT(14) COMMIT(15)
        #undef COMMIT
        sup |= acc;
    }
    __syncthreads();

    for (int r = l; r < NMS_TOPN; r += 64) {
        float4 o = make_float4(0.f, 0.f, 0.f, 0.f);
        if (r < cnt) {
            float4 bx = sortedBoxes[(size_t)b * MCAP + s_sel[r]];
            o.x = fminf(fmaxf(bx.x, 0.f), 1.f);
            o.y = fminf(fmaxf(bx.y, 0.f), 1.f);
            o.z = fminf(fmaxf(bx.z, 0.f), 1.f);
            o.w = fminf(fmaxf(bx.w, 0.f), 1.f);
        }
        selBoxes[(size_t)b * NMS_TOPN + r] = o;
    }
}

// ------------------------------------------------------------------
// Kernel 4: per-batch RoI selection (unchanged).
// ------------------------------------------------------------------
__global__ __launch_bounds__(512) void select_kernel(
    const float4* __restrict__ selBoxes, const float* __restrict__ gt_boxes,
    const int* __restrict__ gt_labels, float4* __restrict__ roiBoxes,
    float4* __restrict__ gtMap, int* __restrict__ labMap)
{
    const int b = blockIdx.x;
    const int t = threadIdx.x;
    __shared__ float4 sb[NMS_TOPN];
    __shared__ float4 gt[GT_M];
    __shared__ float  merged[NMS_TOPN];
    __shared__ int    mgt[NMS_TOPN];
    __shared__ short  order[TOTAL_BOX];

    if (t < NMS_TOPN) sb[t] = selBoxes[(size_t)b * NMS_TOPN + t];
    if (t < GT_M) gt[t] = ((const float4*)gt_boxes)[b * GT_M + t];
    __syncthreads();

    if (t < NMS_TOPN) {
        float4 bx = sb[t];
        float a1 = (bx.z - bx.x) * (bx.w - bx.y);
        float best = -1.f; int arg = 0;
        for (int j = 0; j < GT_M; ++j) {
            float4 g = gt[j];
            float yt = fmaxf(bx.x, g.x), xt = fmaxf(bx.y, g.y);
            float yb = fminf(bx.z, g.z), xb = fminf(bx.w, g.w);
            float inter = fmaxf(yb - yt, 0.f) * fmaxf(xb - xt, 0.f);
            float a2 = (g.z - g.x) * (g.w - g.y);
            float un = a1 + a2 - inter;
            float iou = (un > 0.f) ? (inter / un) : 0.f;
            if (iou > best) { best = iou; arg = j; }
        }
        merged[t] = best; mgt[t] = arg;
    }
    __syncthreads();

    if (t < NMS_TOPN) {
        float mi = merged[t];
        int rank = 0;
        for (int j = 0; j < NMS_TOPN; ++j) {
            float mj = merged[j];
            rank += (mj > mi) || (mj == mi && j < t);
        }
        if (rank < TOTAL_BOX) order[rank] = (short)t;
    }
    __syncthreads();

    if (t < TOTAL_BOX) {
        int i = order[t];
        roiBoxes[(size_t)b * TOTAL_BOX + t] = sb[i];
        float4 g = make_float4(0.f, 0.f, 0.f, 0.f);
        int lab = TOTAL_LABELS - 1;
        if (t < TOTAL_POS) {
            int gi = mgt[i];
            g = gt[gi];
            lab = gt_labels[b * GT_M + gi];
        }
        gtMap[(size_t)b * TOTAL_BOX + t] = g;
        labMap[b * TOTAL_BOX + t] = lab;
    }
}

// ------------------------------------------------------------------
// Kernel 5: crop_and_resize bilinear 7x7 pooling (unchanged).
// ------------------------------------------------------------------
__global__ __launch_bounds__(256) void pool_kernel(
    const float* __restrict__ fm, const float4* __restrict__ roiBoxes,
    float* __restrict__ out)
{
    const int b  = blockIdx.y;
    const int r  = blockIdx.x / POOL_H;
    const int py = blockIdx.x % POOL_H;
    const int t  = threadIdx.x;

    float4 bx = roiBoxes[(size_t)b * TOTAL_BOX + r];
    float y1 = bx.x, x1 = bx.y, y2 = bx.z, x2 = bx.w;

    float iy = (float)py / 6.0f;
    float cy = (y2 - y1) * 63.0f;
    float ys = y1 * 63.0f + iy * cy;
    float fy0 = floorf(ys);
    float wy = ys - fy0;
    int y0i = min(max((int)fy0, 0), FM_H - 1);
    int y1i = min(y0i + 1, FM_H - 1);
    bool vy = (ys >= 0.f) && (ys <= 63.f);

    float cx = (x2 - x1) * 63.0f;
    const float2* f2 = (const float2*)fm;
    float2* o2 = (float2*)out;
    size_t obase = ((((size_t)b * TOTAL_BOX + r) * POOL_H + py) * POOL_W) * 256 + t;
    size_t brow = (size_t)b * FM_H;

    for (int px = 0; px < POOL_W; ++px) {
        float ix = (float)px / 6.0f;
        float xs = x1 * 63.0f + ix * cx;
        float fx0 = floorf(xs);
        float wx = xs - fx0;
        int x0i = min(max((int)fx0, 0), FM_W - 1);
        int x1i = min(x0i + 1, FM_W - 1);
        bool vx = (xs >= 0.f) && (xs <= 63.f);

        float2 g00 = f2[((brow + y0i) * FM_W + x0i) * 256 + t];
        float2 g01 = f2[((brow + y0i) * FM_W + x1i) * 256 + t];
        float2 g10 = f2[((brow + y1i) * FM_W + x0i) * 256 + t];
        float2 g11 = f2[((brow + y1i) * FM_W + x1i) * 256 + t];

        float tx = 1.f - wx, ty = 1.f - wy;
        float top0 = g00.x * tx + g01.x * wx;
        float top1 = g00.y * tx + g01.y * wx;
        float bot0 = g10.x * tx + g11.x * wx;
        float bot1 = g10.y * tx + g11.y * wx;
        float o0 = top0 * ty + bot0 * wy;
        float o1 = top1 * ty + bot1 * wy;
        if (!(vy && vx)) { o0 = 0.f; o1 = 0.f; }
        o2[obase + (size_t)px * 256] = make_float2(o0, o1);
    }
}

// ------------------------------------------------------------------
// Kernel 6: deltas + one-hot scatter (unchanged).
// ------------------------------------------------------------------
__global__ __launch_bounds__(256) void finalize_kernel(
    const float4* __restrict__ roiBoxes, const float4* __restrict__ gtMap,
    const int* __restrict__ labMap, float* __restrict__ out_deltas,
    float* __restrict__ out_labels)
{
    int tid = blockIdx.x * blockDim.x + threadIdx.x;
    if (tid >= BATCH * TOTAL_BOX) return;
    float4 bb = roiBoxes[tid];
    float4 g  = gtMap[tid];
    int lab   = labMap[tid];

    float bw = bb.w - bb.y, bh = bb.z - bb.x;
    float bcx = bb.y + 0.5f * bw, bcy = bb.x + 0.5f * bh;
    float gw = g.w - g.y, gh = g.z - g.x;
    float gcx = g.y + 0.5f * gw, gcy = g.x + 0.5f * gh;
    float bw2 = (bw == 0.f) ? 0.001f : bw;
    float bh2 = (bh == 0.f) ? 0.001f : bh;
    float dx = (gw == 0.f) ? 0.f : (gcx - bcx) / bw2;
    float dy = (gh == 0.f) ? 0.f : (gcy - bcy) / bh2;
    float dw = (gw == 0.f) ? 0.f : logf(fmaxf(gw, 1e-12f) / bw2);
    float dh = (gh == 0.f) ? 0.f : logf(fmaxf(gh, 1e-12f) / bh2);
    float dlt[4] = {dy, dx, dh, dw};

    float* od = out_deltas + (size_t)tid * (TOTAL_LABELS * 4);
    for (int k = 0; k < TOTAL_LABELS * 4; ++k)
        od[k] = ((k >> 2) == lab) ? dlt[k & 3] : 0.f;
    float* ol = out_labels + (size_t)tid * TOTAL_LABELS;
    for (int c = 0; c < TOTAL_LABELS; ++c)
        ol[c] = (c == lab) ? 1.0f : 0.0f;
}

// ------------------------------------------------------------------
extern "C" void kernel_launch(void* const* d_in, const int* in_sizes, int n_in,
                              void* d_out, int out_size, void* d_ws, size_t ws_size,
                              hipStream_t stream) {
    (void)in_sizes; (void)n_in; (void)out_size; (void)ws_size;
    const float* fm         = (const float*)d_in[0];
    const float* rpn_deltas = (const float*)d_in[1];
    const float* rpn_scores = (const float*)d_in[2];
    const float* anchors    = (const float*)d_in[3];
    const float* gt_boxes   = (const float*)d_in[4];
    const int*   gt_labels  = (const int*)d_in[5];
    float* out = (float*)d_out;

    char* w = (char*)d_ws;
    size_t off = 0;
    auto take = [&](size_t bytes) -> char* {
        char* p = w + off;
        off = (off + bytes + 255) & ~(size_t)255;
        return p;
    };
    float4* sortedBoxes = (float4*)take((size_t)BATCH * MCAP * 16);
    u64*    keysG       = (u64*)take((size_t)BATCH * MCAP * 8);
    int*    mCounts     = (int*)take(BATCH * sizeof(int));
    int*    partial     = (int*)take((size_t)BATCH * JCHUNKS * MCAP * 4);  // 1 MB
    float4* selBoxes    = (float4*)take((size_t)BATCH * NMS_TOPN * 16);
    float4* roiBoxes    = (float4*)take((size_t)BATCH * TOTAL_BOX * 16);
    float4* gtMap       = (float4*)take((size_t)BATCH * TOTAL_BOX * 16);
    int*    labMap      = (int*)take((size_t)BATCH * TOTAL_BOX * 4);
    u64*    mask        = (u64*)take((size_t)BATCH * MWORDS * MCAP * 8);   // 8 MB

    compact_kernel<<<BATCH, 1024, 0, stream>>>(rpn_scores, keysG, mCounts);
    rank_partial_kernel<<<dim3(MCAP / 256, JCHUNKS, BATCH), 256, 0, stream>>>(
        keysG, partial);
    rank_finalize_kernel<<<dim3(MCAP / 256, BATCH), 256, 0, stream>>>(
        keysG, anchors, rpn_deltas, mCounts, partial, sortedBoxes);
    nms_mask_kernel<<<dim3(MCAP / 64, MCAP / 256, BATCH), 256, 0, stream>>>(
        sortedBoxes, mask);
    nms_scan_kernel<<<BATCH, 64, 0, stream>>>(sortedBoxes, mCounts, mask, selBoxes);
    select_kernel<<<BATCH, 512, 0, stream>>>(selBoxes, gt_boxes, gt_labels,
                                             roiBoxes, gtMap, labMap);
    pool_kernel<<<dim3(TOTAL_BOX * POOL_H, BATCH), 256, 0, stream>>>(fm, roiBoxes, out);
    finalize_kernel<<<2, 256, 0, stream>>>(roiBoxes, gtMap, labMap,
                                           out + OUT_POOL_ELEMS,
                                           out + OUT_POOL_ELEMS + OUT_DELTA_ELEMS);
}

// Round 12
// 239.833 us; speedup vs baseline: 1.4852x; 1.1621x over previous
//
#include <hip/hip_runtime.h>
#include <math.h>

// ---- problem constants (fixed shapes from reference setup_inputs) ----
#define BATCH      4
#define N_RPN      36864
#define NMS_TOPN   300
#define IOU_THR    0.5f
#define TOTAL_LABELS 21
#define TOTAL_POS  64
#define TOTAL_BOX  128          // TOTAL_POS + TOTAL_NEG
#define GT_M       16
#define FM_H       64
#define FM_W       64
#define FM_C       512
#define POOL_H     7
#define POOL_W     7
#define MCAP       4096         // top-K candidates kept for greedy NMS
#define MWORDS     (MCAP / 64)  // 64 suppression words per row
#define NBUCK      1024
#define JCHUNKS    16           // rank partial decomposition (MCAP/256)

typedef unsigned long long u64;

// out sizes (elements)
#define OUT_POOL_ELEMS   ((size_t)BATCH * TOTAL_BOX * POOL_H * POOL_W * FM_C)   // 12,845,056
#define OUT_DELTA_ELEMS  ((size_t)BATCH * TOTAL_BOX * TOTAL_LABELS * 4)         // 43,008

// ------------------------------------------------------------------
// Kernel 1a: histogram -> threshold -> compact keys to global.
// (unchanged from passing R11)
// ------------------------------------------------------------------
__global__ __launch_bounds__(1024) void compact_kernel(
    const float* __restrict__ scores, u64* __restrict__ keysG,
    int* __restrict__ mCounts)
{
    const int b = blockIdx.x;
    const int t = threadIdx.x;
    const int lane = t & 63;
    const int wave = t >> 6;
    __shared__ unsigned hist[NBUCK];
    __shared__ unsigned s_suf[NBUCK];
    __shared__ unsigned s_wincl[16];
    __shared__ int s_cnt, s_thresh;

    hist[t] = 0u;
    if (t == 0) { s_cnt = 0; s_thresh = NBUCK - 1; }
    __syncthreads();

    const float* sc = scores + (size_t)b * N_RPN;
    for (int i = t; i < N_RPN; i += 1024) {
        int bk = (int)(sc[i] * 1024.0f);
        bk = min(max(bk, 0), NBUCK - 1);
        atomicAdd(&hist[bk], 1u);
    }
    __syncthreads();

    // suffix-inclusive scan: wave-internal via shfl_down, then wave sums
    unsigned v = hist[t];
    #pragma unroll
    for (int off = 1; off < 64; off <<= 1) {
        unsigned o = __shfl_down(v, off, 64);
        if (lane + off < 64) v += o;
    }
    if (lane == 0) s_wincl[wave] = v;     // wave total
    __syncthreads();
    if (wave == 0 && lane < 16) {
        unsigned wv = s_wincl[lane];
        #pragma unroll
        for (int off = 1; off < 16; off <<= 1) {
            unsigned o = __shfl_down(wv, off, 64);
            if (lane + off < 16) wv += o;
        }
        s_wincl[lane] = wv;               // inclusive suffix over waves
    }
    __syncthreads();
    unsigned suf = v + ((wave < 15) ? s_wincl[wave + 1] : 0u);
    s_suf[t] = suf;
    __syncthreads();
    if (suf <= MCAP && (t == 0 || s_suf[t - 1] > MCAP)) s_thresh = t;
    __syncthreads();
    const int thresh = s_thresh;

    u64* kg = keysG + (size_t)b * MCAP;
    for (int i = t; i < N_RPN; i += 1024) {
        float s = sc[i];
        int bk = min(max((int)(s * 1024.0f), 0), NBUCK - 1);
        if (bk >= thresh) {
            int p = atomicAdd(&s_cnt, 1);
            // descending score, ascending index => key desc; keys unique, >0
            kg[p] = ((u64)__float_as_uint(s) << 32) | (unsigned)(~(unsigned)i);
        }
    }
    __syncthreads();
    const int M = s_cnt;
    for (int p = M + t; p < MCAP; p += 1024) kg[p] = 0ULL;
    if (t == 0) mCounts[b] = M;
}

// ------------------------------------------------------------------
// Kernel 1b: partial rank counts, 2-D decomposition for TLP.
// (unchanged from passing R11)
// ------------------------------------------------------------------
__global__ __launch_bounds__(256) void rank_partial_kernel(
    const u64* __restrict__ keysG, int* __restrict__ partial)
{
    const int b  = blockIdx.z;
    const int jc = blockIdx.y;
    const int ic = blockIdx.x;
    const int t  = threadIdx.x;
    __shared__ u64 s_j[256];
    const u64* kg = keysG + (size_t)b * MCAP;
    s_j[t] = kg[jc * 256 + t];
    __syncthreads();

    const int i = ic * 256 + t;
    const u64 ki = kg[i];
    const int jbase = jc * 256;
    int cnt = 0;
    const ulonglong2* k2 = (const ulonglong2*)s_j;
    #pragma unroll 8
    for (int j2 = 0; j2 < 128; ++j2) {
        ulonglong2 kk = k2[j2];           // wave-uniform -> LDS broadcast
        int j = jbase + j2 * 2;
        cnt += (kk.x > ki) || (kk.x == ki && j < i);
        cnt += (kk.y > ki) || (kk.y == ki && (j + 1) < i);
    }
    partial[((size_t)b * JCHUNKS + jc) * MCAP + i] = cnt;
}

// ------------------------------------------------------------------
// Kernel 1c: rank = sum of partials -> decode box into
// sortedBoxes[rank]. (unchanged from passing R11)
// ------------------------------------------------------------------
__global__ __launch_bounds__(256) void rank_finalize_kernel(
    const u64* __restrict__ keysG, const float* __restrict__ anchors,
    const float* __restrict__ deltas, const int* __restrict__ mCounts,
    const int* __restrict__ partial, float4* __restrict__ sortedBoxes)
{
    const int b = blockIdx.y;
    const int t = threadIdx.x;
    const int i = blockIdx.x * 256 + t;

    int rank = 0;
    #pragma unroll
    for (int jc = 0; jc < JCHUNKS; ++jc)
        rank += partial[((size_t)b * JCHUNKS + jc) * MCAP + i];

    const u64 ki = keysG[(size_t)b * MCAP + i];
    const int M = mCounts[b];
    float4 o = make_float4(0.f, 0.f, 0.f, 0.f);
    if (i < M) {
        unsigned idx = ~(unsigned)(ki & 0xFFFFFFFFULL);
        const float* a = anchors + ((size_t)b * N_RPN + idx) * 4;
        const float* d = deltas  + ((size_t)b * N_RPN + idx) * 4;
        float aw  = a[3] - a[1];
        float ah  = a[2] - a[0];
        float acx = a[1] + 0.5f * aw;
        float acy = a[0] + 0.5f * ah;
        float ww  = expf(d[3]) * aw;
        float hh  = expf(d[2]) * ah;
        float cx  = d[1] * aw + acx;
        float cy  = d[0] * ah + acy;
        float y1  = cy - 0.5f * hh;
        float x1  = cx - 0.5f * ww;
        o = make_float4(y1, x1, y1 + hh, x1 + ww);
    }
    sortedBoxes[(size_t)b * MCAP + rank] = o;
}

// ------------------------------------------------------------------
// Kernel 2: suppression bitmask over top-4096, layout mk[word][row].
// (unchanged from passing R11)
// ------------------------------------------------------------------
__global__ __launch_bounds__(256) void nms_mask_kernel(
    const float4* __restrict__ sortedBoxes, u64* __restrict__ mask)
{
    const int b  = blockIdx.z;
    const int r0 = blockIdx.x * 64;
    const int c0 = blockIdx.y * 256;
    u64* mk = mask + (size_t)b * (MWORDS * MCAP);
    const int t  = threadIdx.x;
    const int lr = t & 63;
    const int wq = t >> 6;
    const int r  = r0 + lr;
    const int w  = (c0 >> 6) + wq;

    if (c0 + 255 <= r0) {
        mk[(size_t)w * MCAP + r] = 0ULL;
        return;
    }
    __shared__ float4 s_c[256];
    const float4* sb = sortedBoxes + (size_t)b * MCAP;
    s_c[t] = sb[c0 + t];
    float4 bi = sb[r];
    __syncthreads();

    float ai = (bi.z - bi.x) * (bi.w - bi.y);
    u64 bits = 0ULL;
    const int jb = w * 64;
    if (jb + 63 > r) {
        for (int k = 0; k < 64; ++k) {
            float4 bj = s_c[wq * 64 + k];
            float yt = fmaxf(bi.x, bj.x);
            float xt = fmaxf(bi.y, bj.y);
            float yb = fminf(bi.z, bj.z);
            float xb = fminf(bi.w, bj.w);
            float inter = fmaxf(yb - yt, 0.f) * fmaxf(xb - xt, 0.f);
            float aj = (bj.z - bj.x) * (bj.w - bj.y);
            float un = ai + aj - inter;
            bool sup = (jb + k > r) && (un > 0.f) && ((inter / un) > IOU_THR);
            bits |= ((u64)sup) << k;
        }
    }
    mk[(size_t)w * MCAP + r] = bits;
}

// ------------------------------------------------------------------
// Kernel 3 (REWRITTEN): block-parallel greedy scan. Candidates in
// 64-blocks; per block the greedy subset = kernel of the intra-block
// suppression DAG, found by alternating fixpoint sel <- avw&~kill(sel)
// (converges in ~3-4 iters for sparse suppression; <=66 always, and
// DAG kernels are unique so this equals sequential greedy exactly).
// Eliminates the per-pick ballot/commit dependency chain of R11
// (20 rounds x ~8400cy). Suppression rows of the resolved block are
// loaded with NO ordering dependency: 64 unconditional independent
// loads, cndmask-selected, 16-wide named-reg groups (no spill).
// ------------------------------------------------------------------
__global__ __launch_bounds__(64) void nms_scan_kernel(
    const float4* __restrict__ sortedBoxes, const int* __restrict__ mCounts,
    const u64* __restrict__ mask, float4* __restrict__ selBoxes)
{
    const int b = blockIdx.x;
    const int l = threadIdx.x;
    const u64* mkb = mask + (size_t)b * (MWORDS * MCAP);
    const u64* mkl = mkb + (size_t)l * MCAP;     // lane l's word-plane
    __shared__ int s_sel[NMS_TOPN];
    __shared__ unsigned s_klo, s_khi;
    const int M = mCounts[b];
    u64 sup = 0ULL;                              // lane l holds word l
    int cnt = 0;

    for (int k = 0; k < MWORDS; ++k) {
        if (cnt >= NMS_TOPN) break;
        const int lo_k = k * 64;
        if (lo_k >= M) break;
        const u64 bound = (lo_k + 64 <= M) ? ~0ULL
                                           : ((1ULL << (M - lo_k)) - 1ULL);
        // broadcast suppressed word k (held in lane k) to all lanes
        unsigned blo = (unsigned)__shfl((int)(unsigned)sup, k, 64);
        unsigned bhi = (unsigned)__shfl((int)(unsigned)(sup >> 32), k, 64);
        const u64 avw = ~(((u64)bhi << 32) | (u64)blo) & bound;
        if (avw == 0ULL) continue;

        // diagonal 64x64 sub-mask: lane l = row lo_k+l, word k (coalesced).
        // bits <= l are zero by construction (mask kernel enforces col>row).
        const u64 rw = mkb[(size_t)k * MCAP + lo_k + l];

        // alternating fixpoint -> DAG kernel == sequential greedy subset
        u64 sel = avw;
        for (int it = 0; it < 66; ++it) {
            if (l == 0) { s_klo = 0u; s_khi = 0u; }
            __syncthreads();
            if ((sel >> l) & 1ULL) {
                unsigned rl = (unsigned)rw, rh = (unsigned)(rw >> 32);
                if (rl) atomicOr(&s_klo, rl);
                if (rh) atomicOr(&s_khi, rh);
            }
            __syncthreads();
            u64 kill = ((u64)s_khi << 32) | (u64)s_klo;
            u64 nsel = avw & ~kill;
            if (nsel == sel) break;              // uniform condition
            sel = nsel;
        }

        // rank within block (prefix popcount) + trim to NMS_TOPN total
        const int rank_l = __popcll(sel & ((1ULL << l) - 1ULL));
        int pc = __popcll(sel);
        const int rem = NMS_TOPN - cnt;
        if (pc > rem) {
            sel = __ballot(((sel >> l) & 1ULL) && (rank_l < rem));
            pc = rem;
        }
        if ((sel >> l) & 1ULL) s_sel[cnt + rank_l] = lo_k + l;
        cnt += pc;

        // apply suppression of the selected rows to this lane's word.
        // 64 unconditional independent loads, selected via cndmask.
        if (cnt < NMS_TOPN) {
            u64 acc = 0ULL;
            #define NMS_LD(g, m)  { const int j = (g) * 16 + (m);              \
                const u64 rr = mkl[lo_k + j];                                  \
                q |= (((sel >> j) & 1ULL) ? rr : 0ULL); }
            #define NMS_GRP(g)                                                 \
            if ((sel >> ((g) * 16)) & 0xFFFFULL) {                             \
                u64 q = 0ULL;                                                  \
                NMS_LD(g,0)  NMS_LD(g,1)  NMS_LD(g,2)  NMS_LD(g,3)             \
                NMS_LD(g,4)  NMS_LD(g,5)  NMS_LD(g,6)  NMS_LD(g,7)             \
                NMS_LD(g,8)  NMS_LD(g,9)  NMS_LD(g,10) NMS_LD(g,11)            \
                NMS_LD(g,12) NMS_LD(g,13) NMS_LD(g,14) NMS_LD(g,15)            \
                acc |= q;                                                      \
            }
            NMS_GRP(0) NMS_GRP(1) NMS_GRP(2) NMS_GRP(3)
            #undef NMS_GRP
            #undef NMS_LD
            sup |= acc;
        }
        __syncthreads();
    }
    __syncthreads();

    for (int r = l; r < NMS_TOPN; r += 64) {
        float4 o = make_float4(0.f, 0.f, 0.f, 0.f);
        if (r < cnt) {
            float4 bx = sortedBoxes[(size_t)b * MCAP + s_sel[r]];
            o.x = fminf(fmaxf(bx.x, 0.f), 1.f);
            o.y = fminf(fmaxf(bx.y, 0.f), 1.f);
            o.z = fminf(fmaxf(bx.z, 0.f), 1.f);
            o.w = fminf(fmaxf(bx.w, 0.f), 1.f);
        }
        selBoxes[(size_t)b * NMS_TOPN + r] = o;
    }
}

// ------------------------------------------------------------------
// Kernel 4: per-batch RoI selection (unchanged).
// ------------------------------------------------------------------
__global__ __launch_bounds__(512) void select_kernel(
    const float4* __restrict__ selBoxes, const float* __restrict__ gt_boxes,
    const int* __restrict__ gt_labels, float4* __restrict__ roiBoxes,
    float4* __restrict__ gtMap, int* __restrict__ labMap)
{
    const int b = blockIdx.x;
    const int t = threadIdx.x;
    __shared__ float4 sb[NMS_TOPN];
    __shared__ float4 gt[GT_M];
    __shared__ float  merged[NMS_TOPN];
    __shared__ int    mgt[NMS_TOPN];
    __shared__ short  order[TOTAL_BOX];

    if (t < NMS_TOPN) sb[t] = selBoxes[(size_t)b * NMS_TOPN + t];
    if (t < GT_M) gt[t] = ((const float4*)gt_boxes)[b * GT_M + t];
    __syncthreads();

    if (t < NMS_TOPN) {
        float4 bx = sb[t];
        float a1 = (bx.z - bx.x) * (bx.w - bx.y);
        float best = -1.f; int arg = 0;
        for (int j = 0; j < GT_M; ++j) {
            float4 g = gt[j];
            float yt = fmaxf(bx.x, g.x), xt = fmaxf(bx.y, g.y);
            float yb = fminf(bx.z, g.z), xb = fminf(bx.w, g.w);
            float inter = fmaxf(yb - yt, 0.f) * fmaxf(xb - xt, 0.f);
            float a2 = (g.z - g.x) * (g.w - g.y);
            float un = a1 + a2 - inter;
            float iou = (un > 0.f) ? (inter / un) : 0.f;
            if (iou > best) { best = iou; arg = j; }
        }
        merged[t] = best; mgt[t] = arg;
    }
    __syncthreads();

    if (t < NMS_TOPN) {
        float mi = merged[t];
        int rank = 0;
        for (int j = 0; j < NMS_TOPN; ++j) {
            float mj = merged[j];
            rank += (mj > mi) || (mj == mi && j < t);
        }
        if (rank < TOTAL_BOX) order[rank] = (short)t;
    }
    __syncthreads();

    if (t < TOTAL_BOX) {
        int i = order[t];
        roiBoxes[(size_t)b * TOTAL_BOX + t] = sb[i];
        float4 g = make_float4(0.f, 0.f, 0.f, 0.f);
        int lab = TOTAL_LABELS - 1;
        if (t < TOTAL_POS) {
            int gi = mgt[i];
            g = gt[gi];
            lab = gt_labels[b * GT_M + gi];
        }
        gtMap[(size_t)b * TOTAL_BOX + t] = g;
        labMap[b * TOTAL_BOX + t] = lab;
    }
}

// ------------------------------------------------------------------
// Kernel 5: crop_and_resize bilinear 7x7 pooling (unchanged).
// ------------------------------------------------------------------
__global__ __launch_bounds__(256) void pool_kernel(
    const float* __restrict__ fm, const float4* __restrict__ roiBoxes,
    float* __restrict__ out)
{
    const int b  = blockIdx.y;
    const int r  = blockIdx.x / POOL_H;
    const int py = blockIdx.x % POOL_H;
    const int t  = threadIdx.x;

    float4 bx = roiBoxes[(size_t)b * TOTAL_BOX + r];
    float y1 = bx.x, x1 = bx.y, y2 = bx.z, x2 = bx.w;

    float iy = (float)py / 6.0f;
    float cy = (y2 - y1) * 63.0f;
    float ys = y1 * 63.0f + iy * cy;
    float fy0 = floorf(ys);
    float wy = ys - fy0;
    int y0i = min(max((int)fy0, 0), FM_H - 1);
    int y1i = min(y0i + 1, FM_H - 1);
    bool vy = (ys >= 0.f) && (ys <= 63.f);

    float cx = (x2 - x1) * 63.0f;
    const float2* f2 = (const float2*)fm;
    float2* o2 = (float2*)out;
    size_t obase = ((((size_t)b * TOTAL_BOX + r) * POOL_H + py) * POOL_W) * 256 + t;
    size_t brow = (size_t)b * FM_H;

    for (int px = 0; px < POOL_W; ++px) {
        float ix = (float)px / 6.0f;
        float xs = x1 * 63.0f + ix * cx;
        float fx0 = floorf(xs);
        float wx = xs - fx0;
        int x0i = min(max((int)fx0, 0), FM_W - 1);
        int x1i = min(x0i + 1, FM_W - 1);
        bool vx = (xs >= 0.f) && (xs <= 63.f);

        float2 g00 = f2[((brow + y0i) * FM_W + x0i) * 256 + t];
        float2 g01 = f2[((brow + y0i) * FM_W + x1i) * 256 + t];
        float2 g10 = f2[((brow + y1i) * FM_W + x0i) * 256 + t];
        float2 g11 = f2[((brow + y1i) * FM_W + x1i) * 256 + t];

        float tx = 1.f - wx, ty = 1.f - wy;
        float top0 = g00.x * tx + g01.x * wx;
        float top1 = g00.y * tx + g01.y * wx;
        float bot0 = g10.x * tx + g11.x * wx;
        float bot1 = g10.y * tx + g11.y * wx;
        float o0 = top0 * ty + bot0 * wy;
        float o1 = top1 * ty + bot1 * wy;
        if (!(vy && vx)) { o0 = 0.f; o1 = 0.f; }
        o2[obase + (size_t)px * 256] = make_float2(o0, o1);
    }
}

// ------------------------------------------------------------------
// Kernel 6: deltas + one-hot scatter (unchanged).
// ------------------------------------------------------------------
__global__ __launch_bounds__(256) void finalize_kernel(
    const float4* __restrict__ roiBoxes, const float4* __restrict__ gtMap,
    const int* __restrict__ labMap, float* __restrict__ out_deltas,
    float* __restrict__ out_labels)
{
    int tid = blockIdx.x * blockDim.x + threadIdx.x;
    if (tid >= BATCH * TOTAL_BOX) return;
    float4 bb = roiBoxes[tid];
    float4 g  = gtMap[tid];
    int lab   = labMap[tid];

    float bw = bb.w - bb.y, bh = bb.z - bb.x;
    float bcx = bb.y + 0.5f * bw, bcy = bb.x + 0.5f * bh;
    float gw = g.w - g.y, gh = g.z - g.x;
    float gcx = g.y + 0.5f * gw, gcy = g.x + 0.5f * gh;
    float bw2 = (bw == 0.f) ? 0.001f : bw;
    float bh2 = (bh == 0.f) ? 0.001f : bh;
    float dx = (gw == 0.f) ? 0.f : (gcx - bcx) / bw2;
    float dy = (gh == 0.f) ? 0.f : (gcy - bcy) / bh2;
    float dw = (gw == 0.f) ? 0.f : logf(fmaxf(gw, 1e-12f) / bw2);
    float dh = (gh == 0.f) ? 0.f : logf(fmaxf(gh, 1e-12f) / bh2);
    float dlt[4] = {dy, dx, dh, dw};

    float* od = out_deltas + (size_t)tid * (TOTAL_LABELS * 4);
    for (int k = 0; k < TOTAL_LABELS * 4; ++k)
        od[k] = ((k >> 2) == lab) ? dlt[k & 3] : 0.f;
    float* ol = out_labels + (size_t)tid * TOTAL_LABELS;
    for (int c = 0; c < TOTAL_LABELS; ++c)
        ol[c] = (c == lab) ? 1.0f : 0.0f;
}

// ------------------------------------------------------------------
extern "C" void kernel_launch(void* const* d_in, const int* in_sizes, int n_in,
                              void* d_out, int out_size, void* d_ws, size_t ws_size,
                              hipStream_t stream) {
    (void)in_sizes; (void)n_in; (void)out_size; (void)ws_size;
    const float* fm         = (const float*)d_in[0];
    const float* rpn_deltas = (const float*)d_in[1];
    const float* rpn_scores = (const float*)d_in[2];
    const float* anchors    = (const float*)d_in[3];
    const float* gt_boxes   = (const float*)d_in[4];
    const int*   gt_labels  = (const int*)d_in[5];
    float* out = (float*)d_out;

    char* w = (char*)d_ws;
    size_t off = 0;
    auto take = [&](size_t bytes) -> char* {
        char* p = w + off;
        off = (off + bytes + 255) & ~(size_t)255;
        return p;
    };
    float4* sortedBoxes = (float4*)take((size_t)BATCH * MCAP * 16);
    u64*    keysG       = (u64*)take((size_t)BATCH * MCAP * 8);
    int*    mCounts     = (int*)take(BATCH * sizeof(int));
    int*    partial     = (int*)take((size_t)BATCH * JCHUNKS * MCAP * 4);  // 1 MB
    float4* selBoxes    = (float4*)take((size_t)BATCH * NMS_TOPN * 16);
    float4* roiBoxes    = (float4*)take((size_t)BATCH * TOTAL_BOX * 16);
    float4* gtMap       = (float4*)take((size_t)BATCH * TOTAL_BOX * 16);
    int*    labMap      = (int*)take((size_t)BATCH * TOTAL_BOX * 4);
    u64*    mask        = (u64*)take((size_t)BATCH * MWORDS * MCAP * 8);   // 8 MB

    compact_kernel<<<BATCH, 1024, 0, stream>>>(rpn_scores, keysG, mCounts);
    rank_partial_kernel<<<dim3(MCAP / 256, JCHUNKS, BATCH), 256, 0, stream>>>(
        keysG, partial);
    rank_finalize_kernel<<<dim3(MCAP / 256, BATCH), 256, 0, stream>>>(
        keysG, anchors, rpn_deltas, mCounts, partial, sortedBoxes);
    nms_mask_kernel<<<dim3(MCAP / 64, MCAP / 256, BATCH), 256, 0, stream>>>(
        sortedBoxes, mask);
    nms_scan_kernel<<<BATCH, 64, 0, stream>>>(sortedBoxes, mCounts, mask, selBoxes);
    select_kernel<<<BATCH, 512, 0, stream>>>(selBoxes, gt_boxes, gt_labels,
                                             roiBoxes, gtMap, labMap);
    pool_kernel<<<dim3(TOTAL_BOX * POOL_H, BATCH), 256, 0, stream>>>(fm, roiBoxes, out);
    finalize_kernel<<<2, 256, 0, stream>>>(roiBoxes, gtMap, labMap,
                                           out + OUT_POOL_ELEMS,
                                           out + OUT_POOL_ELEMS + OUT_DELTA_ELEMS);
}